// Round 6
// baseline (327.776 us; speedup 1.0000x reference)
//
#include <hip/hip_runtime.h>

typedef __attribute__((ext_vector_type(8))) short bf16x8;
typedef __attribute__((ext_vector_type(4))) float f32x4;
typedef __attribute__((ext_vector_type(16))) float f32x16;
typedef __attribute__((ext_vector_type(4))) unsigned short us4;
typedef __attribute__((ext_vector_type(8))) unsigned short us8;
typedef __attribute__((ext_vector_type(4))) unsigned int u32x4;

#define B_  8
#define C_  512
#define CI_ 256
#define N_  4096

__device__ __forceinline__ unsigned short f2b(float f) {
  unsigned u = __float_as_uint(f);
  u += 0x7FFFu + ((u >> 16) & 1u);          // RNE
  return (unsigned short)(u >> 16);
}

__device__ __forceinline__ f32x4 mfma16(bf16x8 a, bf16x8 b, f32x4 c) {
  return __builtin_amdgcn_mfma_f32_16x16x32_bf16(a, b, c, 0, 0, 0);
}
__device__ __forceinline__ f32x16 mfma32(bf16x8 a, bf16x8 b, f32x16 c) {
  return __builtin_amdgcn_mfma_f32_32x32x16_bf16(a, b, c, 0, 0, 0);
}

__device__ __forceinline__ void gld16(const void* g, void* l) {
  __builtin_amdgcn_global_load_lds(
      (const __attribute__((address_space(1))) unsigned int*)g,
      (__attribute__((address_space(3))) unsigned int*)l, 16, 0, 0);
}

__device__ __forceinline__ unsigned cvt_pk_bf16(float lo, float hi) {
  unsigned r;
  asm("v_cvt_pk_bf16_f32 %0, %1, %2" : "=v"(r) : "v"(lo), "v"(hi));
  return r;
}

// ---------------------------------------------------------------- fold BN
__global__ void fold_kernel(
  const float* __restrict__ thw, const float* __restrict__ thb,
  const float* __restrict__ thg, const float* __restrict__ thbb,
  const float* __restrict__ thm, const float* __restrict__ thv,
  const float* __restrict__ phw, const float* __restrict__ phb,
  const float* __restrict__ phg, const float* __restrict__ phbb,
  const float* __restrict__ phm, const float* __restrict__ phv,
  const float* __restrict__ gw,  const float* __restrict__ gb,
  const float* __restrict__ wzw, const float* __restrict__ wzb,
  const float* __restrict__ wzg, const float* __restrict__ wzbb,
  const float* __restrict__ wzm, const float* __restrict__ wzv,
  unsigned short* __restrict__ thW, unsigned short* __restrict__ phW,
  unsigned short* __restrict__ gW,  unsigned short* __restrict__ wzW,
  float* __restrict__ bTh, float* __restrict__ bPh,
  float* __restrict__ bG,  float* __restrict__ bWz)
{
  int i = blockIdx.x * 256 + threadIdx.x;
  const int WSZ = CI_ * C_;  // 131072
  if (i < WSZ) { int o = i >> 9; thW[i] = f2b(thw[i] * (thg[o] * rsqrtf(thv[o] + 1e-5f))); return; }
  i -= WSZ;
  if (i < WSZ) { int o = i >> 9; phW[i] = f2b(phw[i] * (phg[o] * rsqrtf(phv[o] + 1e-5f))); return; }
  i -= WSZ;
  if (i < WSZ) { gW[i] = f2b(gw[i]); return; }
  i -= WSZ;
  if (i < WSZ) { int o = i >> 8; wzW[i] = f2b(wzw[i] * (wzg[o] * rsqrtf(wzv[o] + 1e-5f))); return; }
  i -= WSZ;
  if (i < CI_) { float s = thg[i] * rsqrtf(thv[i] + 1e-5f); bTh[i] = (thb[i] - thm[i]) * s + thbb[i]; return; }
  i -= CI_;
  if (i < CI_) { float s = phg[i] * rsqrtf(phv[i] + 1e-5f); bPh[i] = (phb[i] - phm[i]) * s + phbb[i]; return; }
  i -= CI_;
  if (i < CI_) { bG[i] = gb[i]; return; }
  i -= CI_;
  if (i < C_)  { float s = wzg[i] * rsqrtf(wzv[i] + 1e-5f); bWz[i] = (wzb[i] - wzm[i]) * s + wzbb[i]; return; }
}

// ------------------------------------------- x [b][c][n] f32 -> xbT [b][n][c] bf16
__global__ __launch_bounds__(256) void transpose_cast(
  const float* __restrict__ x, unsigned short* __restrict__ xT)
{
  __shared__ float tl[64][68];
  const int b = blockIdx.z, c0 = blockIdx.y * 64, n0 = blockIdx.x * 64;
  const int t = threadIdx.x;
  const int r = t >> 2, q = (t & 3) * 16;
  const float* src = x + ((size_t)(b * C_ + c0 + r)) * N_ + n0 + q;
#pragma unroll
  for (int i = 0; i < 4; i++)
    *(f32x4*)&tl[r][q + i * 4] = *(const f32x4*)(src + i * 4);
  __syncthreads();
  unsigned short* dst = xT + ((size_t)(b * N_ + n0 + r)) * C_ + c0 + q;
  us8 o0, o1;
#pragma unroll
  for (int i = 0; i < 8; i++) o0[i] = f2b(tl[q + i][r]);
#pragma unroll
  for (int i = 0; i < 8; i++) o1[i] = f2b(tl[q + 8 + i][r]);
  *(us8*)dst = o0;
  *(us8*)(dst + 8) = o1;
}

// ------------------------------------------------ BT GEMM, 128x128 tile,
// global_load_lds staging (inverse-swizzled source, swizzled reads), dbuf.
template <int MODE>
__global__ __launch_bounds__(256, 2) void gemm_bt(
  const unsigned short* __restrict__ A,
  const unsigned short* __restrict__ Bm,
  const float* __restrict__ bias,
  const float* __restrict__ resid,
  void* __restrict__ outp,
  int Mdim, int Ndim, int Kdim)
{
  __shared__ __align__(16) unsigned short Al[2][128][64];  // 32KB
  __shared__ __align__(16) unsigned short Bl[2][128][64];  // 32KB
  const int b = blockIdx.z;
  const int m0 = blockIdx.y * 128;
  const int n0 = blockIdx.x * 128;
  const int t = threadIdx.x;
  const int w = t >> 6, l = t & 63, l15 = l & 15, g = l >> 4;
  const int wm = w >> 1, wn = w & 1;
  const int eg = l15 & 7;
  const unsigned short* Bb = Bm + (size_t)b * Ndim * Kdim;
  f32x4 acc[4][4];
#pragma unroll
  for (int i = 0; i < 4; i++)
#pragma unroll
    for (int j = 0; j < 4; j++) acc[i][j] = (f32x4){0.f, 0.f, 0.f, 0.f};

  // staging: 16 gld16 per matrix per K-step (4/wave); inst j covers rows j*8..+7.
  // content swizzle: LDS(row, gl) = global(row, gl ^ (row&7)), granules of 8 elems.
  int aoff[4], boff[4];
#pragma unroll
  for (int i = 0; i < 4; i++) {
    int j = w * 4 + i;
    int row = j * 8 + (l >> 3);
    int sw = ((l & 7) ^ (l >> 3)) * 8;
    aoff[i] = (m0 + row) * Kdim + sw;
    boff[i] = (n0 + row) * Kdim + sw;
  }

#define GSTAGE(bufv, k0v) do { \
    _Pragma("unroll") \
    for (int i_ = 0; i_ < 4; i_++) { \
      gld16(A  + aoff[i_] + (k0v), (unsigned char*)&Al[bufv][0][0] + (w * 4 + i_) * 1024); \
      gld16(Bb + boff[i_] + (k0v), (unsigned char*)&Bl[bufv][0][0] + (w * 4 + i_) * 1024); \
    } \
  } while (0)

  const int nk = Kdim >> 6;
  GSTAGE(0, 0);
  __syncthreads();
  for (int kk = 0; kk < nk; kk++) {
    if (kk + 1 < nk) GSTAGE((kk + 1) & 1, (kk + 1) * 64);
    const int cb = kk & 1;
#pragma unroll
    for (int ks = 0; ks < 2; ks++) {
      bf16x8 af[4], bfr[4];
#pragma unroll
      for (int i = 0; i < 4; i++)
        af[i]  = *(const bf16x8*)&Al[cb][wm * 64 + i * 16 + l15][((ks * 4 + g) ^ eg) * 8];
#pragma unroll
      for (int j = 0; j < 4; j++)
        bfr[j] = *(const bf16x8*)&Bl[cb][wn * 64 + j * 16 + l15][((ks * 4 + g) ^ eg) * 8];
#pragma unroll
      for (int i = 0; i < 4; i++)
#pragma unroll
        for (int j = 0; j < 4; j++)
          acc[i][j] = mfma16(af[i], bfr[j], acc[i][j]);
    }
    __syncthreads();
  }

#pragma unroll
  for (int i = 0; i < 4; i++) {
    int mrow = m0 + wm * 64 + i * 16 + 4 * g;
    f32x4 b4 = *(const f32x4*)&bias[mrow];
#pragma unroll
    for (int j = 0; j < 4; j++) {
      int n = n0 + wn * 64 + j * 16 + l15;
      f32x4 v = acc[i][j];
      v += b4;
      if constexpr (MODE == 0) {
        us4 pk = { f2b(v[0]), f2b(v[1]), f2b(v[2]), f2b(v[3]) };
        *(us4*)((unsigned short*)outp + ((size_t)b * Ndim + n) * Mdim + mrow) = pk;
      } else if constexpr (MODE == 1) {
        unsigned short* o = (unsigned short*)outp + ((size_t)b * Mdim + mrow) * (size_t)Ndim + n;
#pragma unroll
        for (int jj = 0; jj < 4; jj++) o[(size_t)jj * Ndim] = f2b(v[jj]);
      } else {
        size_t base = ((size_t)b * Mdim + mrow) * (size_t)Ndim + n;
        float* o = (float*)outp;
#pragma unroll
        for (int jj = 0; jj < 4; jj++)
          o[base + (size_t)jj * Ndim] = v[jj] + resid[base + (size_t)jj * Ndim];
      }
    }
  }
#undef GSTAGE
}

// -------------------------------------------------------- flash attention
// R4 structure (stage-ahead + single __syncthreads per iter) + split-S ILP
// + tree reductions + cvt_pk packing.
__global__ __launch_bounds__(512, 2) void attn_kernel(
  const unsigned short* __restrict__ thT,
  const unsigned short* __restrict__ phT,
  const unsigned short* __restrict__ gx,
  unsigned short* __restrict__ yT)
{
  __shared__ __align__(16) unsigned char lds[135168]; // 128K KV dbuf + 4K M/L
  const int t = threadIdx.x;
  const int w = t >> 6, l = t & 63, l31 = l & 31, h = l >> 5;
  const int qt = w & 3, mh = w >> 2;
  const int e7 = l31 & 7;
  const int id = blockIdx.x;
  const int b = id & 7;               // XCD-swizzle: one batch per XCD
  const int n0 = (id >> 3) * 128;
  const unsigned short* thB = thT + (size_t)b * N_ * CI_;
  const unsigned short* phB = phT + (size_t)b * N_ * CI_;
  const unsigned short* gxB = gx  + (size_t)b * CI_ * N_;

  // staging source offsets; content swizzle: LDS(row,g) = global(row, g ^ rowbits)
  const int kq = l >> 5, kc = l & 31;
  int koff[4];
#pragma unroll
  for (int i = 0; i < 4; i++) {
    int row = w * 8 + 2 * i + kq;                // K tile row (64 rows)
    koff[i] = row * 256 + ((kc ^ (row & 7)) * 8);
  }
  const int vq = l >> 3, vc = l & 7;
  int voff[4];
#pragma unroll
  for (int i = 0; i < 4; i++) {
    int ci = w * 32 + i * 8 + vq;                // V row (256 ci rows)
    voff[i] = ci * 4096 + ((vc ^ vq) * 8);
  }

#define STAGE(bufv, m0v) do { \
    const unsigned short* kg_ = phB + (size_t)(m0v) * 256; \
    const unsigned short* vg_ = gxB + (m0v); \
    unsigned base_ = (unsigned)(bufv) * 65536u + (unsigned)w * 4096u; \
    _Pragma("unroll") \
    for (int i_ = 0; i_ < 4; i_++) \
      gld16(kg_ + koff[i_], lds + base_ + i_ * 1024); \
    _Pragma("unroll") \
    for (int i_ = 0; i_ < 4; i_++) \
      gld16(vg_ + voff[i_], lds + base_ + 32768u + i_ * 1024); \
  } while (0)

  // Q fragments (B-operand): lane holds Q[n = l31][ci = ks*16 + h*8 + j]
  bf16x8 q[16];
  {
    const unsigned short* qp = thB + (size_t)(n0 + qt * 32 + l31) * CI_ + h * 8;
#pragma unroll
    for (int ks = 0; ks < 16; ks++) q[ks] = *(const bf16x8*)(qp + ks * 16);
  }

  f32x16 acc[8];
#pragma unroll
  for (int i = 0; i < 8; i++)
#pragma unroll
    for (int r = 0; r < 16; r++) acc[i][r] = 0.f;
  float M = -1e30f, L = 0.f;
  const float kS = 0.0625f * 1.44269504f;   // Ci^-0.5 * log2(e)

  STAGE(0, 0);
  __syncthreads();
  int cur = 0;

  for (int tt = 0; tt < 64; tt++) {
    const int m0 = tt * 64;
    if (tt < 63) STAGE(cur ^ 1, m0 + 64);
    const unsigned char* kb = lds + cur * 65536;
    const unsigned char* vb = kb + 32768;

    // S = K * Q over this wave's 32-m half: D[mloc=(r&3)+8*(r>>2)+4h][n=l31]
    // split accumulator: 2 independent MFMA chains for ILP
    f32x16 Sa, Sb;
#pragma unroll
    for (int r = 0; r < 16; r++) { Sa[r] = 0.f; Sb[r] = 0.f; }
#pragma unroll
    for (int ks = 0; ks < 16; ks += 2) {
      bf16x8 kf0 = *(const bf16x8*)(kb + (mh * 32 + l31) * 512 + ((((ks    ) * 2 + h)) ^ e7) * 16);
      bf16x8 kf1 = *(const bf16x8*)(kb + (mh * 32 + l31) * 512 + ((((ks + 1) * 2 + h)) ^ e7) * 16);
      Sa = mfma32(kf0, q[ks], Sa);
      Sb = mfma32(kf1, q[ks + 1], Sb);
    }
    f32x16 S = Sa + Sb;

    // online softmax (per-lane col n = l31), log2 domain; tree reductions
    float m0t = fmaxf(fmaxf(S[0], S[1]),  fmaxf(S[2], S[3]));
    float m1t = fmaxf(fmaxf(S[4], S[5]),  fmaxf(S[6], S[7]));
    float m2t = fmaxf(fmaxf(S[8], S[9]),  fmaxf(S[10], S[11]));
    float m3t = fmaxf(fmaxf(S[12], S[13]), fmaxf(S[14], S[15]));
    float pm = fmaxf(fmaxf(m0t, m1t), fmaxf(m2t, m3t));
    pm *= kS;
    pm = fmaxf(pm, __shfl_xor(pm, 32));
    int dfr = __all(pm <= M + 8.0f);          // defer-max (T13)
    if (!dfr) {
      float nm = fmaxf(M, pm);
      float rs = exp2f(M - nm);
      M = nm; L *= rs;
#pragma unroll
      for (int r = 0; r < 16; r++) {
        float rr = __shfl(rs, h * 32 + ((r & 3) + 8 * (r >> 2) + 4 * h));
#pragma unroll
        for (int c = 0; c < 8; c++) acc[c][r] *= rr;
      }
    }
    float p[16];
#pragma unroll
    for (int r = 0; r < 16; r++) p[r] = exp2f(S[r] * kS - M);
    float s0t = (p[0] + p[1]) + (p[2] + p[3]);
    float s1t = (p[4] + p[5]) + (p[6] + p[7]);
    float s2t = (p[8] + p[9]) + (p[10] + p[11]);
    float s3t = (p[12] + p[13]) + (p[14] + p[15]);
    float rsum = (s0t + s1t) + (s2t + s3t);
    rsum += __shfl_xor(rsum, 32);
    L += rsum;

    // pack P: pk[qq] covers mloc pair base = 2*(qq&1) + 8*(qq>>1) + 4h
    unsigned pk[8];
#pragma unroll
    for (int qq = 0; qq < 8; qq++)
      pk[qq] = cvt_pk_bf16(p[2 * qq], p[2 * qq + 1]);

    // PV: A-frag lane l31 = n, k = mloc; words via shfl_xor(32) + select
#pragma unroll
    for (int ks = 0; ks < 2; ks++) {
      unsigned s00 = pk[ks * 4 + 0], s10 = pk[ks * 4 + 2];
      unsigned s01 = pk[ks * 4 + 1], s11 = pk[ks * 4 + 3];
      unsigned own0 = h ? s10 : s00;
      unsigned snd0 = h ? s00 : s10;
      unsigned own1 = h ? s11 : s01;
      unsigned snd1 = h ? s01 : s11;
      unsigned sw0 = (unsigned)__shfl_xor((int)snd0, 32);
      unsigned sw1 = (unsigned)__shfl_xor((int)snd1, 32);
      u32x4 pv;
      pv[0] = h ? sw0 : own0;
      pv[1] = h ? sw1 : own1;
      pv[2] = h ? own0 : sw0;
      pv[3] = h ? own1 : sw1;
      bf16x8 pa = *(bf16x8*)&pv;
      const int gidx = mh * 4 + ks * 2 + h;   // V granule (0..7)
#pragma unroll
      for (int cit = 0; cit < 8; cit++) {
        bf16x8 vf = *(const bf16x8*)(vb + (cit * 32 + l31) * 128 + ((gidx ^ e7) << 4));
        acc[cit] = mfma32(pa, vf, acc[cit]);
      }
    }
    __syncthreads();
    cur ^= 1;
  }

  // ---- pair-merge (qt, mh=0) <- (qt, mh=1) through LDS
  float* MB = (float*)(lds + 131072);          // [2][4][64]
  float* LB = (float*)(lds + 131072 + 2048);   // [2][4][64]
  MB[mh * 256 + qt * 64 + l] = M;
  LB[mh * 256 + qt * 64 + l] = L;
  float* ab = (float*)lds + qt * 8192 + l;     // 32KB region per qt
  if (mh) {
#pragma unroll
    for (int cit = 0; cit < 8; cit++)
#pragma unroll
      for (int r = 0; r < 16; r++)
        ab[(cit * 16 + r) * 64] = acc[cit][r];
  }
  __syncthreads();
  if (!mh) {
    unsigned short* yB = yT + (size_t)b * N_ * CI_;
#pragma unroll
    for (int r = 0; r < 16; r++) {
      int nl = (r & 3) + 8 * (r >> 2) + 4 * h;
      int li = qt * 64 + h * 32 + nl;
      float M1 = MB[li], L1 = LB[li];
      float M2 = MB[256 + li], L2 = LB[256 + li];
      float Mf = fmaxf(M1, M2);
      float s1 = exp2f(M1 - Mf), s2 = exp2f(M2 - Mf);
      float invf = 1.0f / (L1 * s1 + L2 * s2);
      s1 *= invf; s2 *= invf;
      int n = n0 + qt * 32 + nl;
#pragma unroll
      for (int cit = 0; cit < 8; cit++) {
        float v = acc[cit][r] * s1 + ab[(cit * 16 + r) * 64] * s2;
        yB[(size_t)n * CI_ + cit * 32 + l31] = f2b(v);
      }
    }
  }
#undef STAGE
}

// ---------------------------------------------------------------- host
extern "C" void kernel_launch(void* const* d_in, const int* in_sizes, int n_in,
                              void* d_out, int out_size, void* d_ws, size_t ws_size,
                              hipStream_t stream)
{
  const float* x    = (const float*)d_in[0];
  const float* thw  = (const float*)d_in[1];
  const float* thb  = (const float*)d_in[2];
  const float* thg  = (const float*)d_in[3];
  const float* thbb = (const float*)d_in[4];
  const float* thm  = (const float*)d_in[5];
  const float* thv  = (const float*)d_in[6];
  const float* phw  = (const float*)d_in[7];
  const float* phb  = (const float*)d_in[8];
  const float* phg  = (const float*)d_in[9];
  const float* phbb = (const float*)d_in[10];
  const float* phm  = (const float*)d_in[11];
  const float* phv  = (const float*)d_in[12];
  const float* gw   = (const float*)d_in[13];
  const float* gb   = (const float*)d_in[14];
  const float* wzw  = (const float*)d_in[15];
  const float* wzb  = (const float*)d_in[16];
  const float* wzg  = (const float*)d_in[17];
  const float* wzbb = (const float*)d_in[18];
  const float* wzm  = (const float*)d_in[19];
  const float* wzv  = (const float*)d_in[20];

  char* ws = (char*)d_ws;
  unsigned short* xbT = (unsigned short*)(ws);                    // 32 MB  [b][n][c]
  unsigned short* thT = (unsigned short*)(ws + 33554432ull);      // 16 MB  [b][n][ci]
  unsigned short* phT = (unsigned short*)(ws + 50331648ull);      // 16 MB  [b][n][ci]
  unsigned short* gxb = (unsigned short*)(ws + 67108864ull);      // 16 MB  [b][ci][n]
  unsigned short* yT  = (unsigned short*)(ws + 83886080ull);      // 16 MB  [b][n][ci]
  unsigned short* thW = (unsigned short*)(ws + 100663296ull);     // 256 KB
  unsigned short* phW = (unsigned short*)(ws + 100925440ull);
  unsigned short* gW  = (unsigned short*)(ws + 101187584ull);
  unsigned short* wzW = (unsigned short*)(ws + 101449728ull);
  float* bTh = (float*)(ws + 101711872ull);
  float* bPh = (float*)(ws + 101712896ull);
  float* bG  = (float*)(ws + 101713920ull);
  float* bWz = (float*)(ws + 101714944ull);

  fold_kernel<<<2053, 256, 0, stream>>>(
      thw, thb, thg, thbb, thm, thv,
      phw, phb, phg, phbb, phm, phv,
      gw, gb, wzw, wzb, wzg, wzbb, wzm, wzv,
      thW, phW, gW, wzW, bTh, bPh, bG, bWz);

  transpose_cast<<<dim3(64, 8, 8), 256, 0, stream>>>(x, xbT);

  gemm_bt<0><<<dim3(32, 2, 8), 256, 0, stream>>>(thW, xbT, bTh, nullptr, thT, CI_, N_, C_);
  gemm_bt<0><<<dim3(32, 2, 8), 256, 0, stream>>>(phW, xbT, bPh, nullptr, phT, CI_, N_, C_);
  gemm_bt<1><<<dim3(32, 2, 8), 256, 0, stream>>>(gW,  xbT, bG,  nullptr, gxb, CI_, N_, C_);

  attn_kernel<<<dim3(256), 512, 0, stream>>>(thT, phT, gxb, yT);

  gemm_bt<2><<<dim3(32, 4, 8), 256, 0, stream>>>(wzW, yT, bWz, x, d_out, C_, N_, CI_);
}

// Round 7
// 288.916 us; speedup vs baseline: 1.1345x; 1.1345x over previous
//
#include <hip/hip_runtime.h>

typedef __attribute__((ext_vector_type(8))) short bf16x8;
typedef __attribute__((ext_vector_type(4))) float f32x4;
typedef __attribute__((ext_vector_type(16))) float f32x16;
typedef __attribute__((ext_vector_type(4))) unsigned short us4;
typedef __attribute__((ext_vector_type(8))) unsigned short us8;
typedef __attribute__((ext_vector_type(4))) unsigned int u32x4;

#define B_  8
#define C_  512
#define CI_ 256
#define N_  4096

__device__ __forceinline__ unsigned short f2b(float f) {
  unsigned u = __float_as_uint(f);
  u += 0x7FFFu + ((u >> 16) & 1u);          // RNE
  return (unsigned short)(u >> 16);
}

__device__ __forceinline__ f32x4 mfma16(bf16x8 a, bf16x8 b, f32x4 c) {
  return __builtin_amdgcn_mfma_f32_16x16x32_bf16(a, b, c, 0, 0, 0);
}
__device__ __forceinline__ f32x16 mfma32(bf16x8 a, bf16x8 b, f32x16 c) {
  return __builtin_amdgcn_mfma_f32_32x32x16_bf16(a, b, c, 0, 0, 0);
}

__device__ __forceinline__ void gld16(const void* g, void* l) {
  __builtin_amdgcn_global_load_lds(
      (const __attribute__((address_space(1))) unsigned int*)g,
      (__attribute__((address_space(3))) unsigned int*)l, 16, 0, 0);
}

// ---------------------------------------------------------------- fold BN
__global__ void fold_kernel(
  const float* __restrict__ thw, const float* __restrict__ thb,
  const float* __restrict__ thg, const float* __restrict__ thbb,
  const float* __restrict__ thm, const float* __restrict__ thv,
  const float* __restrict__ phw, const float* __restrict__ phb,
  const float* __restrict__ phg, const float* __restrict__ phbb,
  const float* __restrict__ phm, const float* __restrict__ phv,
  const float* __restrict__ gw,  const float* __restrict__ gb,
  const float* __restrict__ wzw, const float* __restrict__ wzb,
  const float* __restrict__ wzg, const float* __restrict__ wzbb,
  const float* __restrict__ wzm, const float* __restrict__ wzv,
  unsigned short* __restrict__ thW, unsigned short* __restrict__ phW,
  unsigned short* __restrict__ gW,  unsigned short* __restrict__ wzW,
  float* __restrict__ bTh, float* __restrict__ bPh,
  float* __restrict__ bG,  float* __restrict__ bWz)
{
  int i = blockIdx.x * 256 + threadIdx.x;
  const int WSZ = CI_ * C_;  // 131072
  if (i < WSZ) { int o = i >> 9; thW[i] = f2b(thw[i] * (thg[o] * rsqrtf(thv[o] + 1e-5f))); return; }
  i -= WSZ;
  if (i < WSZ) { int o = i >> 9; phW[i] = f2b(phw[i] * (phg[o] * rsqrtf(phv[o] + 1e-5f))); return; }
  i -= WSZ;
  if (i < WSZ) { gW[i] = f2b(gw[i]); return; }
  i -= WSZ;
  if (i < WSZ) { int o = i >> 8; wzW[i] = f2b(wzw[i] * (wzg[o] * rsqrtf(wzv[o] + 1e-5f))); return; }
  i -= WSZ;
  if (i < CI_) { float s = thg[i] * rsqrtf(thv[i] + 1e-5f); bTh[i] = (thb[i] - thm[i]) * s + thbb[i]; return; }
  i -= CI_;
  if (i < CI_) { float s = phg[i] * rsqrtf(phv[i] + 1e-5f); bPh[i] = (phb[i] - phm[i]) * s + phbb[i]; return; }
  i -= CI_;
  if (i < CI_) { bG[i] = gb[i]; return; }
  i -= CI_;
  if (i < C_)  { float s = wzg[i] * rsqrtf(wzv[i] + 1e-5f); bWz[i] = (wzb[i] - wzm[i]) * s + wzbb[i]; return; }
}

// ------------------------------------------- x [b][c][n] f32 -> xbT [b][n][c] bf16
__global__ __launch_bounds__(256) void transpose_cast(
  const float* __restrict__ x, unsigned short* __restrict__ xT)
{
  __shared__ float tl[64][68];
  const int b = blockIdx.z, c0 = blockIdx.y * 64, n0 = blockIdx.x * 64;
  const int t = threadIdx.x;
  const int r = t >> 2, q = (t & 3) * 16;
  const float* src = x + ((size_t)(b * C_ + c0 + r)) * N_ + n0 + q;
#pragma unroll
  for (int i = 0; i < 4; i++)
    *(f32x4*)&tl[r][q + i * 4] = *(const f32x4*)(src + i * 4);
  __syncthreads();
  unsigned short* dst = xT + ((size_t)(b * N_ + n0 + r)) * C_ + c0 + q;
  us8 o0, o1;
#pragma unroll
  for (int i = 0; i < 8; i++) o0[i] = f2b(tl[q + i][r]);
#pragma unroll
  for (int i = 0; i < 8; i++) o1[i] = f2b(tl[q + 8 + i][r]);
  *(us8*)dst = o0;
  *(us8*)(dst + 8) = o1;
}

// ------------------------------------------------ BT GEMM, 128x128 tile,
// global_load_lds staging (inverse-swizzled source, swizzled reads), dbuf.
template <int MODE>
__global__ __launch_bounds__(256, 2) void gemm_bt(
  const unsigned short* __restrict__ A,
  const unsigned short* __restrict__ Bm,
  const float* __restrict__ bias,
  const float* __restrict__ resid,
  void* __restrict__ outp,
  int Mdim, int Ndim, int Kdim)
{
  __shared__ __align__(16) unsigned short Al[2][128][64];  // 32KB
  __shared__ __align__(16) unsigned short Bl[2][128][64];  // 32KB
  const int b = blockIdx.z;
  const int m0 = blockIdx.y * 128;
  const int n0 = blockIdx.x * 128;
  const int t = threadIdx.x;
  const int w = t >> 6, l = t & 63, l15 = l & 15, g = l >> 4;
  const int wm = w >> 1, wn = w & 1;
  const int eg = l15 & 7;
  const unsigned short* Bb = Bm + (size_t)b * Ndim * Kdim;
  f32x4 acc[4][4];
#pragma unroll
  for (int i = 0; i < 4; i++)
#pragma unroll
    for (int j = 0; j < 4; j++) acc[i][j] = (f32x4){0.f, 0.f, 0.f, 0.f};

  int aoff[4], boff[4];
#pragma unroll
  for (int i = 0; i < 4; i++) {
    int j = w * 4 + i;
    int row = j * 8 + (l >> 3);
    int sw = ((l & 7) ^ (l >> 3)) * 8;
    aoff[i] = (m0 + row) * Kdim + sw;
    boff[i] = (n0 + row) * Kdim + sw;
  }

#define GSTAGE(bufv, k0v) do { \
    _Pragma("unroll") \
    for (int i_ = 0; i_ < 4; i_++) { \
      gld16(A  + aoff[i_] + (k0v), (unsigned char*)&Al[bufv][0][0] + (w * 4 + i_) * 1024); \
      gld16(Bb + boff[i_] + (k0v), (unsigned char*)&Bl[bufv][0][0] + (w * 4 + i_) * 1024); \
    } \
  } while (0)

  const int nk = Kdim >> 6;
  GSTAGE(0, 0);
  __syncthreads();
  for (int kk = 0; kk < nk; kk++) {
    if (kk + 1 < nk) GSTAGE((kk + 1) & 1, (kk + 1) * 64);
    const int cb = kk & 1;
#pragma unroll
    for (int ks = 0; ks < 2; ks++) {
      bf16x8 af[4], bfr[4];
#pragma unroll
      for (int i = 0; i < 4; i++)
        af[i]  = *(const bf16x8*)&Al[cb][wm * 64 + i * 16 + l15][((ks * 4 + g) ^ eg) * 8];
#pragma unroll
      for (int j = 0; j < 4; j++)
        bfr[j] = *(const bf16x8*)&Bl[cb][wn * 64 + j * 16 + l15][((ks * 4 + g) ^ eg) * 8];
#pragma unroll
      for (int i = 0; i < 4; i++)
#pragma unroll
        for (int j = 0; j < 4; j++)
          acc[i][j] = mfma16(af[i], bfr[j], acc[i][j]);
    }
    __syncthreads();
  }

#pragma unroll
  for (int i = 0; i < 4; i++) {
    int mrow = m0 + wm * 64 + i * 16 + 4 * g;
    f32x4 b4 = *(const f32x4*)&bias[mrow];
#pragma unroll
    for (int j = 0; j < 4; j++) {
      int n = n0 + wn * 64 + j * 16 + l15;
      f32x4 v = acc[i][j];
      v += b4;
      if constexpr (MODE == 0) {
        us4 pk = { f2b(v[0]), f2b(v[1]), f2b(v[2]), f2b(v[3]) };
        *(us4*)((unsigned short*)outp + ((size_t)b * Ndim + n) * Mdim + mrow) = pk;
      } else if constexpr (MODE == 1) {
        unsigned short* o = (unsigned short*)outp + ((size_t)b * Mdim + mrow) * (size_t)Ndim + n;
#pragma unroll
        for (int jj = 0; jj < 4; jj++) o[(size_t)jj * Ndim] = f2b(v[jj]);
      } else {
        size_t base = ((size_t)b * Mdim + mrow) * (size_t)Ndim + n;
        float* o = (float*)outp;
#pragma unroll
        for (int jj = 0; jj < 4; jj++)
          o[base + (size_t)jj * Ndim] = v[jj] + resid[base + (size_t)jj * Ndim];
      }
    }
  }
#undef GSTAGE
}

// -------------------------------------------------------- flash attention
// 512 thr, 8 waves (qt = w&3, mh = w>>2). QK(t) ∥ PV(t-1) software pipeline:
// K 2-deep (64KB) + V 3-deep (96KB) LDS; per iter: s_barrier -> issue stage
// (t+1) -> counted vmcnt(8) -> interleaved 16 QK + 16 PV MFMA -> softmax(t).
__global__ __launch_bounds__(512, 2) void attn_kernel(
  const unsigned short* __restrict__ thT,
  const unsigned short* __restrict__ phT,
  const unsigned short* __restrict__ gx,
  unsigned short* __restrict__ yT)
{
  __shared__ __align__(16) unsigned char lds[163840]; // K:2x32K | V:3x32K
  const int t = threadIdx.x;
  const int w = t >> 6, l = t & 63, l31 = l & 31, h = l >> 5;
  const int qt = w & 3, mh = w >> 2;
  const int e7 = l31 & 7;
  const int id = blockIdx.x;
  const int b = id & 7;               // XCD-swizzle: one batch per XCD
  const int n0 = (id >> 3) * 128;
  const unsigned short* thB = thT + (size_t)b * N_ * CI_;
  const unsigned short* phB = phT + (size_t)b * N_ * CI_;
  const unsigned short* gxB = gx  + (size_t)b * CI_ * N_;

  // staging source offsets; content swizzle: LDS(row,g) = global(row, g ^ rowbits)
  const int kq = l >> 5, kc = l & 31;
  int koff[4];
#pragma unroll
  for (int i = 0; i < 4; i++) {
    int row = w * 8 + 2 * i + kq;                // K tile row (64 rows)
    koff[i] = row * 256 + ((kc ^ (row & 7)) * 8);
  }
  const int vq = l >> 3, vc = l & 7;
  int voff[4];
#pragma unroll
  for (int i = 0; i < 4; i++) {
    int ci = w * 32 + i * 8 + vq;                // V row (256 ci rows)
    voff[i] = ci * 4096 + ((vc ^ vq) * 8);
  }

#define STAGE_K(slot, m0v) do { \
    const unsigned short* kg_ = phB + (size_t)(m0v) * 256; \
    _Pragma("unroll") \
    for (int i_ = 0; i_ < 4; i_++) \
      gld16(kg_ + koff[i_], lds + (unsigned)(slot) * 32768u + (unsigned)w * 4096u + i_ * 1024u); \
  } while (0)
#define STAGE_V(slot, m0v) do { \
    const unsigned short* vg_ = gxB + (m0v); \
    _Pragma("unroll") \
    for (int i_ = 0; i_ < 4; i_++) \
      gld16(vg_ + voff[i_], lds + 65536u + (unsigned)(slot) * 32768u + (unsigned)w * 4096u + i_ * 1024u); \
  } while (0)

  // Q fragments (B-operand): lane holds Q[n = l31][ci = ks*16 + h*8 + j]
  bf16x8 q[16];
  {
    const unsigned short* qp = thB + (size_t)(n0 + qt * 32 + l31) * CI_ + h * 8;
#pragma unroll
    for (int ks = 0; ks < 16; ks++) q[ks] = *(const bf16x8*)(qp + ks * 16);
  }

  f32x16 acc[8];
#pragma unroll
  for (int i = 0; i < 8; i++)
#pragma unroll
    for (int r = 0; r < 16; r++) acc[i][r] = 0.f;
  float M = -1e30f, L = 0.f;
  unsigned pkp[8];                          // packed P(t-1)
  const float kS = 0.0625f * 1.44269504f;   // Ci^-0.5 * log2(e)

#define SOFTMAX_UPDATE(Sv) do { \
    float pm_ = Sv[0]; \
    _Pragma("unroll") for (int r = 1; r < 16; r++) pm_ = fmaxf(pm_, Sv[r]); \
    pm_ *= kS; \
    pm_ = fmaxf(pm_, __shfl_xor(pm_, 32)); \
    int dfr_ = __all(pm_ <= M + 8.0f); \
    if (!dfr_) { \
      float nm_ = fmaxf(M, pm_); \
      float rs_ = exp2f(M - nm_); \
      M = nm_; L *= rs_; \
      _Pragma("unroll") for (int r = 0; r < 16; r++) { \
        float rr_ = __shfl(rs_, h * 32 + ((r & 3) + 8 * (r >> 2) + 4 * h)); \
        _Pragma("unroll") for (int c = 0; c < 8; c++) acc[c][r] *= rr_; \
      } \
    } \
    float p_[16]; float rsum_ = 0.f; \
    _Pragma("unroll") for (int r = 0; r < 16; r++) { p_[r] = exp2f(Sv[r] * kS - M); rsum_ += p_[r]; } \
    rsum_ += __shfl_xor(rsum_, 32); \
    L += rsum_; \
    _Pragma("unroll") for (int qq = 0; qq < 8; qq++) \
      pkp[qq] = ((unsigned)f2b(p_[2 * qq + 1]) << 16) | f2b(p_[2 * qq]); \
  } while (0)

#define BUILD_PA(pa0v, pa1v) do { \
    u32x4 pv0_, pv1_; \
    { unsigned s00 = pkp[0], s10 = pkp[2], s01 = pkp[1], s11 = pkp[3]; \
      unsigned own0 = h ? s10 : s00, snd0 = h ? s00 : s10; \
      unsigned own1 = h ? s11 : s01, snd1 = h ? s01 : s11; \
      unsigned sw0 = (unsigned)__shfl_xor((int)snd0, 32); \
      unsigned sw1 = (unsigned)__shfl_xor((int)snd1, 32); \
      pv0_[0] = h ? sw0 : own0; pv0_[1] = h ? sw1 : own1; \
      pv0_[2] = h ? own0 : sw0; pv0_[3] = h ? own1 : sw1; } \
    { unsigned s00 = pkp[4], s10 = pkp[6], s01 = pkp[5], s11 = pkp[7]; \
      unsigned own0 = h ? s10 : s00, snd0 = h ? s00 : s10; \
      unsigned own1 = h ? s11 : s01, snd1 = h ? s01 : s11; \
      unsigned sw0 = (unsigned)__shfl_xor((int)snd0, 32); \
      unsigned sw1 = (unsigned)__shfl_xor((int)snd1, 32); \
      pv1_[0] = h ? sw0 : own0; pv1_[1] = h ? sw1 : own1; \
      pv1_[2] = h ? own0 : sw0; pv1_[3] = h ? own1 : sw1; } \
    pa0v = *(bf16x8*)&pv0_; pa1v = *(bf16x8*)&pv1_; \
  } while (0)

  // prologue: stage tile 0
  STAGE_K(0, 0); STAGE_V(0, 0);

  // ---- iteration 0 (peeled: QK + softmax only)
  __builtin_amdgcn_s_barrier();
  STAGE_K(1, 64); STAGE_V(1, 64);
  asm volatile("s_waitcnt vmcnt(8)" ::: "memory");
  {
    const unsigned char* kb = lds;
    f32x16 S;
#pragma unroll
    for (int r = 0; r < 16; r++) S[r] = 0.f;
#pragma unroll
    for (int u = 0; u < 16; u++) {
      bf16x8 kf = *(const bf16x8*)(kb + (mh * 32 + l31) * 512 + (((u * 2 + h)) ^ e7) * 16);
      S = mfma32(kf, q[u], S);
    }
    SOFTMAX_UPDATE(S);
  }

  int vprev = 0, vstage = 2;
  for (int tt = 1; tt < 64; tt++) {
    __builtin_amdgcn_s_barrier();
    if (tt < 63) {
      STAGE_K((tt + 1) & 1, (tt + 1) * 64);
      STAGE_V(vstage, (tt + 1) * 64);
      asm volatile("s_waitcnt vmcnt(8)" ::: "memory");
    } else {
      asm volatile("s_waitcnt vmcnt(0)" ::: "memory");
    }
    const unsigned char* kb  = lds + (unsigned)(tt & 1) * 32768u;
    const unsigned char* vbp = lds + 65536u + (unsigned)vprev * 32768u;

    bf16x8 pa0, pa1;
    BUILD_PA(pa0, pa1);

    f32x16 S;
#pragma unroll
    for (int r = 0; r < 16; r++) S[r] = 0.f;
    // interleaved: QK(tt) chain + PV(tt-1) independent chains
#pragma unroll
    for (int u = 0; u < 16; u++) {
      bf16x8 kf = *(const bf16x8*)(kb + (mh * 32 + l31) * 512 + (((u * 2 + h)) ^ e7) * 16);
      S = mfma32(kf, q[u], S);
      const int ksv = u >> 3, cit = u & 7;
      bf16x8 vf = *(const bf16x8*)(vbp + (cit * 32 + l31) * 128 + (((mh * 4 + ksv * 2 + h) ^ e7) << 4));
      acc[cit] = mfma32(ksv ? pa1 : pa0, vf, acc[cit]);
    }
    SOFTMAX_UPDATE(S);
    vprev  = (vprev  == 2) ? 0 : vprev + 1;
    vstage = (vstage == 2) ? 0 : vstage + 1;
  }

  // ---- epilogue PV(63): V slot = vprev (== 0)
  {
    const unsigned char* vbp = lds + 65536u + (unsigned)vprev * 32768u;
    bf16x8 pa0, pa1;
    BUILD_PA(pa0, pa1);
#pragma unroll
    for (int ksv = 0; ksv < 2; ksv++)
#pragma unroll
      for (int cit = 0; cit < 8; cit++) {
        bf16x8 vf = *(const bf16x8*)(vbp + (cit * 32 + l31) * 128 + (((mh * 4 + ksv * 2 + h) ^ e7) << 4));
        acc[cit] = mfma32(ksv ? pa1 : pa0, vf, acc[cit]);
      }
  }
  __syncthreads();

  // ---- pair-merge (qt, mh=0) <- (qt, mh=1) through LDS (R4-proven)
  float* MB = (float*)(lds + 131072);          // [2][4][64]
  float* LB = (float*)(lds + 131072 + 2048);   // [2][4][64]
  MB[mh * 256 + qt * 64 + l] = M;
  LB[mh * 256 + qt * 64 + l] = L;
  float* ab = (float*)lds + qt * 8192 + l;     // 32KB region per qt
  if (mh) {
#pragma unroll
    for (int cit = 0; cit < 8; cit++)
#pragma unroll
      for (int r = 0; r < 16; r++)
        ab[(cit * 16 + r) * 64] = acc[cit][r];
  }
  __syncthreads();
  if (!mh) {
    unsigned short* yB = yT + (size_t)b * N_ * CI_;
#pragma unroll
    for (int r = 0; r < 16; r++) {
      int nl = (r & 3) + 8 * (r >> 2) + 4 * h;
      int li = qt * 64 + h * 32 + nl;
      float M1 = MB[li], L1 = LB[li];
      float M2 = MB[256 + li], L2 = LB[256 + li];
      float Mf = fmaxf(M1, M2);
      float s1 = exp2f(M1 - Mf), s2 = exp2f(M2 - Mf);
      float invf = 1.0f / (L1 * s1 + L2 * s2);
      s1 *= invf; s2 *= invf;
      int n = n0 + qt * 32 + nl;
#pragma unroll
      for (int cit = 0; cit < 8; cit++) {
        float v = acc[cit][r] * s1 + ab[(cit * 16 + r) * 64] * s2;
        yB[(size_t)n * CI_ + cit * 32 + l31] = f2b(v);
      }
    }
  }
#undef STAGE_K
#undef STAGE_V
#undef SOFTMAX_UPDATE
#undef BUILD_PA
}

// ---------------------------------------------------------------- host
extern "C" void kernel_launch(void* const* d_in, const int* in_sizes, int n_in,
                              void* d_out, int out_size, void* d_ws, size_t ws_size,
                              hipStream_t stream)
{
  const float* x    = (const float*)d_in[0];
  const float* thw  = (const float*)d_in[1];
  const float* thb  = (const float*)d_in[2];
  const float* thg  = (const float*)d_in[3];
  const float* thbb = (const float*)d_in[4];
  const float* thm  = (const float*)d_in[5];
  const float* thv  = (const float*)d_in[6];
  const float* phw  = (const float*)d_in[7];
  const float* phb  = (const float*)d_in[8];
  const float* phg  = (const float*)d_in[9];
  const float* phbb = (const float*)d_in[10];
  const float* phm  = (const float*)d_in[11];
  const float* phv  = (const float*)d_in[12];
  const float* gw   = (const float*)d_in[13];
  const float* gb   = (const float*)d_in[14];
  const float* wzw  = (const float*)d_in[15];
  const float* wzb  = (const float*)d_in[16];
  const float* wzg  = (const float*)d_in[17];
  const float* wzbb = (const float*)d_in[18];
  const float* wzm  = (const float*)d_in[19];
  const float* wzv  = (const float*)d_in[20];

  char* ws = (char*)d_ws;
  unsigned short* xbT = (unsigned short*)(ws);                    // 32 MB  [b][n][c]
  unsigned short* thT = (unsigned short*)(ws + 33554432ull);      // 16 MB  [b][n][ci]
  unsigned short* phT = (unsigned short*)(ws + 50331648ull);      // 16 MB  [b][n][ci]
  unsigned short* gxb = (unsigned short*)(ws + 67108864ull);      // 16 MB  [b][ci][n]
  unsigned short* yT  = (unsigned short*)(ws + 83886080ull);      // 16 MB  [b][n][ci]
  unsigned short* thW = (unsigned short*)(ws + 100663296ull);     // 256 KB
  unsigned short* phW = (unsigned short*)(ws + 100925440ull);
  unsigned short* gW  = (unsigned short*)(ws + 101187584ull);
  unsigned short* wzW = (unsigned short*)(ws + 101449728ull);
  float* bTh = (float*)(ws + 101711872ull);
  float* bPh = (float*)(ws + 101712896ull);
  float* bG  = (float*)(ws + 101713920ull);
  float* bWz = (float*)(ws + 101714944ull);

  fold_kernel<<<2053, 256, 0, stream>>>(
      thw, thb, thg, thbb, thm, thv,
      phw, phb, phg, phbb, phm, phv,
      gw, gb, wzw, wzb, wzg, wzbb, wzm, wzv,
      thW, phW, gW, wzW, bTh, bPh, bG, bWz);

  transpose_cast<<<dim3(64, 8, 8), 256, 0, stream>>>(x, xbT);

  gemm_bt<0><<<dim3(32, 2, 8), 256, 0, stream>>>(thW, xbT, bTh, nullptr, thT, CI_, N_, C_);
  gemm_bt<0><<<dim3(32, 2, 8), 256, 0, stream>>>(phW, xbT, bPh, nullptr, phT, CI_, N_, C_);
  gemm_bt<1><<<dim3(32, 2, 8), 256, 0, stream>>>(gW,  xbT, bG,  nullptr, gxb, CI_, N_, C_);

  attn_kernel<<<dim3(256), 512, 0, stream>>>(thT, phT, gxb, yT);

  gemm_bt<2><<<dim3(32, 4, 8), 256, 0, stream>>>(wzW, yT, bWz, x, d_out, C_, N_, CI_);
}

// Round 8
// 279.663 us; speedup vs baseline: 1.1720x; 1.0331x over previous
//
#include <hip/hip_runtime.h>
#include <hip/hip_bf16.h>

typedef __attribute__((ext_vector_type(8))) short bf16x8;
typedef __attribute__((ext_vector_type(4))) float f32x4;
typedef __attribute__((ext_vector_type(16))) float f32x16;
typedef __attribute__((ext_vector_type(4))) unsigned short us4;
typedef __attribute__((ext_vector_type(8))) unsigned short us8;
typedef __attribute__((ext_vector_type(4))) unsigned int u32x4;

#define B_  8
#define C_  512
#define CI_ 256
#define N_  4096

__device__ __forceinline__ unsigned short f2b(float f) {
  unsigned u = __float_as_uint(f);
  u += 0x7FFFu + ((u >> 16) & 1u);          // RNE
  return (unsigned short)(u >> 16);
}

__device__ __forceinline__ unsigned pkbf16(float lo, float hi) {
  union { __hip_bfloat162 h2; unsigned u; } cv;
  cv.h2 = __float22bfloat162_rn(make_float2(lo, hi));
  return cv.u;
}

__device__ __forceinline__ f32x4 mfma16(bf16x8 a, bf16x8 b, f32x4 c) {
  return __builtin_amdgcn_mfma_f32_16x16x32_bf16(a, b, c, 0, 0, 0);
}
__device__ __forceinline__ f32x16 mfma32(bf16x8 a, bf16x8 b, f32x16 c) {
  return __builtin_amdgcn_mfma_f32_32x32x16_bf16(a, b, c, 0, 0, 0);
}

__device__ __forceinline__ void gld16(const void* g, void* l) {
  __builtin_amdgcn_global_load_lds(
      (const __attribute__((address_space(1))) unsigned int*)g,
      (__attribute__((address_space(3))) unsigned int*)l, 16, 0, 0);
}

// ---------------------------------------------------------------- fold BN
__global__ void fold_kernel(
  const float* __restrict__ thw, const float* __restrict__ thb,
  const float* __restrict__ thg, const float* __restrict__ thbb,
  const float* __restrict__ thm, const float* __restrict__ thv,
  const float* __restrict__ phw, const float* __restrict__ phb,
  const float* __restrict__ phg, const float* __restrict__ phbb,
  const float* __restrict__ phm, const float* __restrict__ phv,
  const float* __restrict__ gw,  const float* __restrict__ gb,
  const float* __restrict__ wzw, const float* __restrict__ wzb,
  const float* __restrict__ wzg, const float* __restrict__ wzbb,
  const float* __restrict__ wzm, const float* __restrict__ wzv,
  unsigned short* __restrict__ thW, unsigned short* __restrict__ phW,
  unsigned short* __restrict__ gW,  unsigned short* __restrict__ wzW,
  float* __restrict__ bTh, float* __restrict__ bPh,
  float* __restrict__ bG,  float* __restrict__ bWz)
{
  int i = blockIdx.x * 256 + threadIdx.x;
  const int WSZ = CI_ * C_;  // 131072
  if (i < WSZ) { int o = i >> 9; thW[i] = f2b(thw[i] * (thg[o] * rsqrtf(thv[o] + 1e-5f))); return; }
  i -= WSZ;
  if (i < WSZ) { int o = i >> 9; phW[i] = f2b(phw[i] * (phg[o] * rsqrtf(phv[o] + 1e-5f))); return; }
  i -= WSZ;
  if (i < WSZ) { gW[i] = f2b(gw[i]); return; }
  i -= WSZ;
  if (i < WSZ) { int o = i >> 8; wzW[i] = f2b(wzw[i] * (wzg[o] * rsqrtf(wzv[o] + 1e-5f))); return; }
  i -= WSZ;
  if (i < CI_) { float s = thg[i] * rsqrtf(thv[i] + 1e-5f); bTh[i] = (thb[i] - thm[i]) * s + thbb[i]; return; }
  i -= CI_;
  if (i < CI_) { float s = phg[i] * rsqrtf(phv[i] + 1e-5f); bPh[i] = (phb[i] - phm[i]) * s + phbb[i]; return; }
  i -= CI_;
  if (i < CI_) { bG[i] = gb[i]; return; }
  i -= CI_;
  if (i < C_)  { float s = wzg[i] * rsqrtf(wzv[i] + 1e-5f); bWz[i] = (wzb[i] - wzm[i]) * s + wzbb[i]; return; }
}

// ------------------------------------------- x [b][c][n] f32 -> xbT [b][n][c] bf16
__global__ __launch_bounds__(256) void transpose_cast(
  const float* __restrict__ x, unsigned short* __restrict__ xT)
{
  __shared__ float tl[64][68];
  const int b = blockIdx.z, c0 = blockIdx.y * 64, n0 = blockIdx.x * 64;
  const int t = threadIdx.x;
  const int r = t >> 2, q = (t & 3) * 16;
  const float* src = x + ((size_t)(b * C_ + c0 + r)) * N_ + n0 + q;
#pragma unroll
  for (int i = 0; i < 4; i++)
    *(f32x4*)&tl[r][q + i * 4] = *(const f32x4*)(src + i * 4);
  __syncthreads();
  unsigned short* dst = xT + ((size_t)(b * N_ + n0 + r)) * C_ + c0 + q;
  us8 o0, o1;
#pragma unroll
  for (int i = 0; i < 8; i++) o0[i] = f2b(tl[q + i][r]);
#pragma unroll
  for (int i = 0; i < 8; i++) o1[i] = f2b(tl[q + 8 + i][r]);
  *(us8*)dst = o0;
  *(us8*)(dst + 8) = o1;
}

// ------------------------------------------------ BT GEMM, 128x128 tile,
// global_load_lds staging (inverse-swizzled source, swizzled reads), dbuf.
template <int MODE>
__global__ __launch_bounds__(256, 2) void gemm_bt(
  const unsigned short* __restrict__ A,
  const unsigned short* __restrict__ Bm,
  const float* __restrict__ bias,
  const float* __restrict__ resid,
  void* __restrict__ outp,
  int Mdim, int Ndim, int Kdim)
{
  __shared__ __align__(16) unsigned short Al[2][128][64];  // 32KB
  __shared__ __align__(16) unsigned short Bl[2][128][64];  // 32KB
  const int b = blockIdx.z;
  const int m0 = blockIdx.y * 128;
  const int n0 = blockIdx.x * 128;
  const int t = threadIdx.x;
  const int w = t >> 6, l = t & 63, l15 = l & 15, g = l >> 4;
  const int wm = w >> 1, wn = w & 1;
  const int eg = l15 & 7;
  const unsigned short* Bb = Bm + (size_t)b * Ndim * Kdim;
  f32x4 acc[4][4];
#pragma unroll
  for (int i = 0; i < 4; i++)
#pragma unroll
    for (int j = 0; j < 4; j++) acc[i][j] = (f32x4){0.f, 0.f, 0.f, 0.f};

  int aoff[4], boff[4];
#pragma unroll
  for (int i = 0; i < 4; i++) {
    int j = w * 4 + i;
    int row = j * 8 + (l >> 3);
    int sw = ((l & 7) ^ (l >> 3)) * 8;
    aoff[i] = (m0 + row) * Kdim + sw;
    boff[i] = (n0 + row) * Kdim + sw;
  }

#define GSTAGE(bufv, k0v) do { \
    _Pragma("unroll") \
    for (int i_ = 0; i_ < 4; i_++) { \
      gld16(A  + aoff[i_] + (k0v), (unsigned char*)&Al[bufv][0][0] + (w * 4 + i_) * 1024); \
      gld16(Bb + boff[i_] + (k0v), (unsigned char*)&Bl[bufv][0][0] + (w * 4 + i_) * 1024); \
    } \
  } while (0)

  const int nk = Kdim >> 6;
  GSTAGE(0, 0);
  __syncthreads();
  for (int kk = 0; kk < nk; kk++) {
    if (kk + 1 < nk) GSTAGE((kk + 1) & 1, (kk + 1) * 64);
    const int cb = kk & 1;
#pragma unroll
    for (int ks = 0; ks < 2; ks++) {
      bf16x8 af[4], bfr[4];
#pragma unroll
      for (int i = 0; i < 4; i++)
        af[i]  = *(const bf16x8*)&Al[cb][wm * 64 + i * 16 + l15][((ks * 4 + g) ^ eg) * 8];
#pragma unroll
      for (int j = 0; j < 4; j++)
        bfr[j] = *(const bf16x8*)&Bl[cb][wn * 64 + j * 16 + l15][((ks * 4 + g) ^ eg) * 8];
#pragma unroll
      for (int i = 0; i < 4; i++)
#pragma unroll
        for (int j = 0; j < 4; j++)
          acc[i][j] = mfma16(af[i], bfr[j], acc[i][j]);
    }
    __syncthreads();
  }

#pragma unroll
  for (int i = 0; i < 4; i++) {
    int mrow = m0 + wm * 64 + i * 16 + 4 * g;
    f32x4 b4 = *(const f32x4*)&bias[mrow];
#pragma unroll
    for (int j = 0; j < 4; j++) {
      int n = n0 + wn * 64 + j * 16 + l15;
      f32x4 v = acc[i][j];
      v += b4;
      if constexpr (MODE == 0) {
        us4 pk = { f2b(v[0]), f2b(v[1]), f2b(v[2]), f2b(v[3]) };
        *(us4*)((unsigned short*)outp + ((size_t)b * Ndim + n) * Mdim + mrow) = pk;
      } else if constexpr (MODE == 1) {
        unsigned short* o = (unsigned short*)outp + ((size_t)b * Mdim + mrow) * (size_t)Ndim + n;
#pragma unroll
        for (int jj = 0; jj < 4; jj++) o[(size_t)jj * Ndim] = f2b(v[jj]);
      } else {
        size_t base = ((size_t)b * Mdim + mrow) * (size_t)Ndim + n;
        float* o = (float*)outp;
#pragma unroll
        for (int jj = 0; jj < 4; jj++)
          o[base + (size_t)jj * Ndim] = v[jj] + resid[base + (size_t)jj * Ndim];
      }
    }
  }
#undef GSTAGE
}

// -------------------------------------------------------- flash attention
// R4-exact loop (best measured: 220us): 512 thr, 8 waves (qt=w&3, mh=w>>2),
// 64-row K/V tiles double-buffered (128KB), stage-ahead + single
// __syncthreads per iter. Only delta vs R4: P packing via v_cvt_pk fusion.
__global__ __launch_bounds__(512, 2) void attn_kernel(
  const unsigned short* __restrict__ thT,
  const unsigned short* __restrict__ phT,
  const unsigned short* __restrict__ gx,
  unsigned short* __restrict__ yT)
{
  __shared__ __align__(16) unsigned char lds[135168]; // 128K KV dbuf + 4K M/L
  const int t = threadIdx.x;
  const int w = t >> 6, l = t & 63, l31 = l & 31, h = l >> 5;
  const int qt = w & 3, mh = w >> 2;
  const int e7 = l31 & 7;
  const int id = blockIdx.x;
  const int b = id & 7;               // XCD-swizzle: one batch per XCD
  const int n0 = (id >> 3) * 128;
  const unsigned short* thB = thT + (size_t)b * N_ * CI_;
  const unsigned short* phB = phT + (size_t)b * N_ * CI_;
  const unsigned short* gxB = gx  + (size_t)b * CI_ * N_;

  // staging source offsets; content swizzle: LDS(row,g) = global(row, g ^ rowbits)
  const int kq = l >> 5, kc = l & 31;
  int koff[4];
#pragma unroll
  for (int i = 0; i < 4; i++) {
    int row = w * 8 + 2 * i + kq;                // K tile row (64 rows)
    koff[i] = row * 256 + ((kc ^ (row & 7)) * 8);
  }
  const int vq = l >> 3, vc = l & 7;
  int voff[4];
#pragma unroll
  for (int i = 0; i < 4; i++) {
    int ci = w * 32 + i * 8 + vq;                // V row (256 ci rows)
    voff[i] = ci * 4096 + ((vc ^ vq) * 8);
  }

#define STAGE(bufv, m0v) do { \
    const unsigned short* kg_ = phB + (size_t)(m0v) * 256; \
    const unsigned short* vg_ = gxB + (m0v); \
    unsigned base_ = (unsigned)(bufv) * 65536u + (unsigned)w * 4096u; \
    _Pragma("unroll") \
    for (int i_ = 0; i_ < 4; i_++) \
      gld16(kg_ + koff[i_], lds + base_ + i_ * 1024); \
    _Pragma("unroll") \
    for (int i_ = 0; i_ < 4; i_++) \
      gld16(vg_ + voff[i_], lds + base_ + 32768u + i_ * 1024); \
  } while (0)

  // Q fragments (B-operand): lane holds Q[n = l31][ci = ks*16 + h*8 + j]
  bf16x8 q[16];
  {
    const unsigned short* qp = thB + (size_t)(n0 + qt * 32 + l31) * CI_ + h * 8;
#pragma unroll
    for (int ks = 0; ks < 16; ks++) q[ks] = *(const bf16x8*)(qp + ks * 16);
  }

  f32x16 acc[8];
#pragma unroll
  for (int i = 0; i < 8; i++)
#pragma unroll
    for (int r = 0; r < 16; r++) acc[i][r] = 0.f;
  float M = -1e30f, L = 0.f;
  const float kS = 0.0625f * 1.44269504f;   // Ci^-0.5 * log2(e)

  STAGE(0, 0);
  __syncthreads();
  int cur = 0;

  for (int tt = 0; tt < 64; tt++) {
    const int m0 = tt * 64;
    if (tt < 63) STAGE(cur ^ 1, m0 + 64);
    const unsigned char* kb = lds + cur * 65536;
    const unsigned char* vb = kb + 32768;

    // S = K * Q over this wave's 32-m half: D[mloc=(r&3)+8*(r>>2)+4h][n=l31]
    f32x16 S;
#pragma unroll
    for (int r = 0; r < 16; r++) S[r] = 0.f;
#pragma unroll
    for (int ks = 0; ks < 16; ks++) {
      bf16x8 kf = *(const bf16x8*)(kb + (mh * 32 + l31) * 512 + ((((ks * 2 + h)) ^ e7) << 4));
      S = mfma32(kf, q[ks], S);
    }

    // online softmax (per-lane col n = l31), log2 domain
    float pm = S[0];
#pragma unroll
    for (int r = 1; r < 16; r++) pm = fmaxf(pm, S[r]);
    pm *= kS;
    pm = fmaxf(pm, __shfl_xor(pm, 32));
    int dfr = __all(pm <= M + 8.0f);          // defer-max (T13)
    if (!dfr) {
      float nm = fmaxf(M, pm);
      float rs = exp2f(M - nm);
      M = nm; L *= rs;
#pragma unroll
      for (int r = 0; r < 16; r++) {
        float rr = __shfl(rs, h * 32 + ((r & 3) + 8 * (r >> 2) + 4 * h));
#pragma unroll
        for (int c = 0; c < 8; c++) acc[c][r] *= rr;
      }
    }
    float p[16];
    float rsum = 0.f;
#pragma unroll
    for (int r = 0; r < 16; r++) {
      p[r] = exp2f(S[r] * kS - M);
      rsum += p[r];
    }
    rsum += __shfl_xor(rsum, 32);
    L += rsum;

    // pack P: pk[qq] covers mloc pair base = 2*(qq&1) + 8*(qq>>1) + 4h
    unsigned pk[8];
#pragma unroll
    for (int qq = 0; qq < 8; qq++)
      pk[qq] = pkbf16(p[2 * qq], p[2 * qq + 1]);

    // PV: A-frag lane l31 = n, k = mloc; words via shfl_xor(32) + select
#pragma unroll
    for (int ks = 0; ks < 2; ks++) {
      unsigned s00 = pk[ks * 4 + 0], s10 = pk[ks * 4 + 2];
      unsigned s01 = pk[ks * 4 + 1], s11 = pk[ks * 4 + 3];
      unsigned own0 = h ? s10 : s00;
      unsigned snd0 = h ? s00 : s10;
      unsigned own1 = h ? s11 : s01;
      unsigned snd1 = h ? s01 : s11;
      unsigned sw0 = (unsigned)__shfl_xor((int)snd0, 32);
      unsigned sw1 = (unsigned)__shfl_xor((int)snd1, 32);
      u32x4 pv;
      pv[0] = h ? sw0 : own0;
      pv[1] = h ? sw1 : own1;
      pv[2] = h ? own0 : sw0;
      pv[3] = h ? own1 : sw1;
      bf16x8 pa = *(bf16x8*)&pv;
      const int gidx = mh * 4 + ks * 2 + h;   // V granule (0..7)
#pragma unroll
      for (int cit = 0; cit < 8; cit++) {
        bf16x8 vf = *(const bf16x8*)(vb + (cit * 32 + l31) * 128 + ((gidx ^ e7) << 4));
        acc[cit] = mfma32(pa, vf, acc[cit]);
      }
    }
    __syncthreads();
    cur ^= 1;
  }

  // ---- pair-merge (qt, mh=0) <- (qt, mh=1) through LDS
  float* MB = (float*)(lds + 131072);          // [2][4][64]
  float* LB = (float*)(lds + 131072 + 2048);   // [2][4][64]
  MB[mh * 256 + qt * 64 + l] = M;
  LB[mh * 256 + qt * 64 + l] = L;
  float* ab = (float*)lds + qt * 8192 + l;     // 32KB region per qt
  if (mh) {
#pragma unroll
    for (int cit = 0; cit < 8; cit++)
#pragma unroll
      for (int r = 0; r < 16; r++)
        ab[(cit * 16 + r) * 64] = acc[cit][r];
  }
  __syncthreads();
  if (!mh) {
    unsigned short* yB = yT + (size_t)b * N_ * CI_;
#pragma unroll
    for (int r = 0; r < 16; r++) {
      int nl = (r & 3) + 8 * (r >> 2) + 4 * h;
      int li = qt * 64 + h * 32 + nl;
      float M1 = MB[li], L1 = LB[li];
      float M2 = MB[256 + li], L2 = LB[256 + li];
      float Mf = fmaxf(M1, M2);
      float s1 = exp2f(M1 - Mf), s2 = exp2f(M2 - Mf);
      float invf = 1.0f / (L1 * s1 + L2 * s2);
      s1 *= invf; s2 *= invf;
      int n = n0 + qt * 32 + nl;
#pragma unroll
      for (int cit = 0; cit < 8; cit++) {
        float v = acc[cit][r] * s1 + ab[(cit * 16 + r) * 64] * s2;
        yB[(size_t)n * CI_ + cit * 32 + l31] = f2b(v);
      }
    }
  }
#undef STAGE
}

// ---------------------------------------------------------------- host
extern "C" void kernel_launch(void* const* d_in, const int* in_sizes, int n_in,
                              void* d_out, int out_size, void* d_ws, size_t ws_size,
                              hipStream_t stream)
{
  const float* x    = (const float*)d_in[0];
  const float* thw  = (const float*)d_in[1];
  const float* thb  = (const float*)d_in[2];
  const float* thg  = (const float*)d_in[3];
  const float* thbb = (const float*)d_in[4];
  const float* thm  = (const float*)d_in[5];
  const float* thv  = (const float*)d_in[6];
  const float* phw  = (const float*)d_in[7];
  const float* phb  = (const float*)d_in[8];
  const float* phg  = (const float*)d_in[9];
  const float* phbb = (const float*)d_in[10];
  const float* phm  = (const float*)d_in[11];
  const float* phv  = (const float*)d_in[12];
  const float* gw   = (const float*)d_in[13];
  const float* gb   = (const float*)d_in[14];
  const float* wzw  = (const float*)d_in[15];
  const float* wzb  = (const float*)d_in[16];
  const float* wzg  = (const float*)d_in[17];
  const float* wzbb = (const float*)d_in[18];
  const float* wzm  = (const float*)d_in[19];
  const float* wzv  = (const float*)d_in[20];

  char* ws = (char*)d_ws;
  unsigned short* xbT = (unsigned short*)(ws);                    // 32 MB  [b][n][c]
  unsigned short* thT = (unsigned short*)(ws + 33554432ull);      // 16 MB  [b][n][ci]
  unsigned short* phT = (unsigned short*)(ws + 50331648ull);      // 16 MB  [b][n][ci]
  unsigned short* gxb = (unsigned short*)(ws + 67108864ull);      // 16 MB  [b][ci][n]
  unsigned short* yT  = (unsigned short*)(ws + 83886080ull);      // 16 MB  [b][n][ci]
  unsigned short* thW = (unsigned short*)(ws + 100663296ull);     // 256 KB
  unsigned short* phW = (unsigned short*)(ws + 100925440ull);
  unsigned short* gW  = (unsigned short*)(ws + 101187584ull);
  unsigned short* wzW = (unsigned short*)(ws + 101449728ull);
  float* bTh = (float*)(ws + 101711872ull);
  float* bPh = (float*)(ws + 101712896ull);
  float* bG  = (float*)(ws + 101713920ull);
  float* bWz = (float*)(ws + 101714944ull);

  fold_kernel<<<2053, 256, 0, stream>>>(
      thw, thb, thg, thbb, thm, thv,
      phw, phb, phg, phbb, phm, phv,
      gw, gb, wzw, wzb, wzg, wzbb, wzm, wzv,
      thW, phW, gW, wzW, bTh, bPh, bG, bWz);

  transpose_cast<<<dim3(64, 8, 8), 256, 0, stream>>>(x, xbT);

  gemm_bt<0><<<dim3(32, 2, 8), 256, 0, stream>>>(thW, xbT, bTh, nullptr, thT, CI_, N_, C_);
  gemm_bt<0><<<dim3(32, 2, 8), 256, 0, stream>>>(phW, xbT, bPh, nullptr, phT, CI_, N_, C_);
  gemm_bt<1><<<dim3(32, 2, 8), 256, 0, stream>>>(gW,  xbT, bG,  nullptr, gxb, CI_, N_, C_);

  attn_kernel<<<dim3(256), 512, 0, stream>>>(thT, phT, gxb, yT);

  gemm_bt<2><<<dim3(32, 4, 8), 256, 0, stream>>>(wzW, yT, bWz, x, d_out, C_, N_, CI_);
}